// Round 11
// baseline (156.443 us; speedup 1.0000x reference)
//
#include <hip/hip_runtime.h>
#include <hip/hip_bf16.h>

// CLIP loss: B=8192, D=1024, temp=0.5.
// loss = mean_i [ 0.5*(log sum_j exp(s_ij) + log sum_j exp(s_ji)) - s_ii ],
// s = (zi_n @ zj_n^T) * 2.  |s| <= 2 -> exp safe, no max trick.
//
// R11 = R10 with MFMA shape 16x16x128 -> 32x32x64 (mfma_scale_32x32x64):
// 32 FLOP per LDS-byte vs 16 -> halves ds_read traffic (R10's dominant term,
// 44% of window). acc[2][2] f32x16 = 64 regs under the (256,2) cap that
// R9/R10 proved spill-free. Everything else identical to R10: 128x128 tile,
// 4 waves (2x2), BK=128B, double-buffer, counted vmcnt(8), L2 supertile
// swizzle (FETCH 37MB), chunk swizzle cphys = clog ^ (row&7) both sides.
//
// ws: [0,8M) zi8 (x2 temp folded), [8M,16M) zj8, [16M,18M) rp[64][8192],
//     [18M,20M) cp[64][8192], [20M,+32K) dg[8192], then part[32].

using f32x16 = __attribute__((ext_vector_type(16))) float;
using i32x8  = __attribute__((ext_vector_type(8))) int;
using i32x4  = __attribute__((ext_vector_type(4))) int;

#define USCL 0x7F7F7F7Fu   // E8M0 = 127 -> scale 1.0 in every byte

__device__ __forceinline__ void async16(const unsigned char* g, unsigned char* l) {
    __builtin_amdgcn_global_load_lds(
        (const __attribute__((address_space(1))) void*)g,
        (__attribute__((address_space(3))) void*)l, 16, 0, 0);
}

// ---- kernel 1: row-normalize fp32 -> fp8 e4m3, extra scale folded ----
__global__ __launch_bounds__(256) void clip_norm_k(const float* __restrict__ in,
                                                   unsigned int* __restrict__ out,
                                                   float extra) {
    int row = blockIdx.x;
    const float4* ip = reinterpret_cast<const float4*>(in + (size_t)row * 1024);
    float4 v = ip[threadIdx.x];
    float ss = v.x * v.x + v.y * v.y + v.z * v.z + v.w * v.w;
    #pragma unroll
    for (int o = 1; o < 64; o <<= 1) ss += __shfl_xor(ss, o);
    __shared__ float sb[4];
    if ((threadIdx.x & 63) == 0) sb[threadIdx.x >> 6] = ss;
    __syncthreads();
    float tot = sb[0] + sb[1] + sb[2] + sb[3];
    float scl = extra / fmaxf(sqrtf(tot), 1e-12f);
    int p = __builtin_amdgcn_cvt_pk_fp8_f32(v.x * scl, v.y * scl, 0, false);
    p = __builtin_amdgcn_cvt_pk_fp8_f32(v.z * scl, v.w * scl, p, true);
    out[(size_t)row * 256 + threadIdx.x] = (unsigned int)p;
}

// Read a 32B fp8 A/B fragment for 32x32x64: row in tile (l&31), k-subtile
// ks (0,1 within BK=128B), kblk = l>>5 (k = kblk*32 + byte).
// Row = 8 chunks of 16B, phys = log ^ (row&7).
__device__ __forceinline__ i32x8 ldfrag32(const unsigned char* buf, int row,
                                          int ks, int kblk) {
    int c0 = (ks * 4 + kblk * 2) ^ (row & 7);
    int c1 = (ks * 4 + kblk * 2 + 1) ^ (row & 7);
    i32x4 lo = *reinterpret_cast<const i32x4*>(buf + row * 128 + c0 * 16);
    i32x4 hi = *reinterpret_cast<const i32x4*>(buf + row * 128 + c1 * 16);
    i32x8 r;
    r[0] = lo[0]; r[1] = lo[1]; r[2] = lo[2]; r[3] = lo[3];
    r[4] = hi[0]; r[5] = hi[1]; r[6] = hi[2]; r[7] = hi[3];
    return r;
}

__global__ __launch_bounds__(256, 2) void clip_gemm_k(
    const unsigned char* __restrict__ A,   // zi8 [8192][1024]
    const unsigned char* __restrict__ Bm,  // zj8 [8192][1024]
    float* __restrict__ rp, float* __restrict__ cp, float* __restrict__ dg) {
    __shared__ unsigned char bA0[16384], bB0[16384], bA1[16384], bB1[16384];
    __shared__ float rbuf[2][128];
    __shared__ float cbuf[2][128];

    // L2-supertile swizzle (R10-verified: FETCH 266->37 MB).
    const int c_x = blockIdx.x & 7;
    const int q = blockIdx.x >> 3;           // 0..511
    const int s = q >> 6;                    // supertile 0..7 (temporal)
    const int p = q & 63;                    // position in 8x8 supertile
    const int bi = c_x * 8 + (p >> 3);       // 0..63
    const int bj = s * 8 + (p & 7);          // 0..63
    const int tid = threadIdx.x;
    const int l = tid & 63, w = tid >> 6;
    const int wm = w >> 1, wn = w & 1;       // 2x2 wave grid, per-wave 64x64
    const int lane31 = l & 31, kb = l >> 5;

    f32x16 acc[2][2] = {};                   // [fm][fn] 32x32 frags

    const unsigned char* Ag = A + (size_t)(bi * 128) * 1024;
    const unsigned char* Bg = Bm + (size_t)(bj * 128) * 1024;

    // per-thread staging offsets (4 sweeps x 256 thr x 16B = one [128][128B] buf)
    int soff[4];
    #pragma unroll
    for (int u = 0; u < 4; ++u) {
        int idx = u * 256 + tid;
        int srow = idx >> 3;
        int clog = idx & 7;
        soff[u] = srow * 1024 + ((clog ^ (srow & 7)) * 16);
    }
    const int ldst = tid * 16;   // linear dest within each sweep block

#define STAGE(ktB, bufA, bufB)                                            \
    _Pragma("unroll") for (int u = 0; u < 4; ++u)                         \
        async16(Ag + (ktB) + soff[u], (bufA) + u * 4096 + ldst);          \
    _Pragma("unroll") for (int u = 0; u < 4; ++u)                         \
        async16(Bg + (ktB) + soff[u], (bufB) + u * 4096 + ldst);

    // prologue: stage tiles 0,1; wait tile 0 (tile1's 8 outstanding)
    STAGE(0, bA0, bB0)
    STAGE(128, bA1, bB1)
    asm volatile("s_waitcnt vmcnt(8)" ::: "memory");
    __builtin_amdgcn_s_barrier();
    __builtin_amdgcn_sched_barrier(0);

    for (int t = 0; t < 8; ++t) {
        const unsigned char* Ac = (t & 1) ? bA1 : bA0;
        const unsigned char* Bc = (t & 1) ? bB1 : bB0;
        unsigned char* Asg = (t & 1) ? bA1 : bA0;
        unsigned char* Bsg = (t & 1) ? bB1 : bB0;

        // open region: 16 ds_read_b128 + 8 MFMA, compiler schedules
        #pragma unroll
        for (int ks = 0; ks < 2; ++ks) {
            i32x8 af[2], bfr[2];
            #pragma unroll
            for (int fm = 0; fm < 2; ++fm)
                af[fm] = ldfrag32(Ac, wm * 64 + fm * 32 + lane31, ks, kb);
            #pragma unroll
            for (int fn = 0; fn < 2; ++fn)
                bfr[fn] = ldfrag32(Bc, wn * 64 + fn * 32 + lane31, ks, kb);
            #pragma unroll
            for (int fm = 0; fm < 2; ++fm)
                #pragma unroll
                for (int fn = 0; fn < 2; ++fn)
                    acc[fm][fn] = __builtin_amdgcn_mfma_scale_f32_32x32x64_f8f6f4(
                        af[fm], bfr[fn], acc[fm][fn], 0, 0, 0, USCL, 0, USCL);
        }

        asm volatile("s_waitcnt lgkmcnt(0)" ::: "memory");
        __builtin_amdgcn_s_barrier();        // all waves done reading this buf
        if (t <= 5) {
            STAGE((t + 2) * 128, Asg, Bsg)
            asm volatile("s_waitcnt vmcnt(8)" ::: "memory");   // t+1 landed
        } else if (t == 6) {
            asm volatile("s_waitcnt vmcnt(0)" ::: "memory");   // t=7 landed
        }
        if (t <= 6) {
            __builtin_amdgcn_s_barrier();
            __builtin_amdgcn_sched_barrier(0);
        }
    }
#undef STAGE

    // ---- epilogue (R6-verified 32x32 C/D mapping, absmax 0.0) ----
    // col = l&31, row = (reg&3) + 8*(reg>>2) + 4*(l>>5).
    if (bi == bj && wm == wn) {
        #pragma unroll
        for (int fm = 0; fm < 2; ++fm)
            #pragma unroll
            for (int reg = 0; reg < 16; ++reg) {
                int rif = (reg & 3) + 8 * (reg >> 2) + 4 * kb;
                if (rif == lane31)
                    dg[bi * 128 + wm * 64 + fm * 32 + lane31] = acc[fm][fm][reg];
            }
    }

    #pragma unroll
    for (int fm = 0; fm < 2; ++fm)
        #pragma unroll
        for (int fn = 0; fn < 2; ++fn)
            #pragma unroll
            for (int reg = 0; reg < 16; ++reg)
                acc[fm][fn][reg] = exp2f(acc[fm][fn][reg] * 1.44269504f);

    // row sums over this wave's 64 cols (fn pair + 32-lane butterfly)
    #pragma unroll
    for (int fm = 0; fm < 2; ++fm) {
        #pragma unroll
        for (int reg = 0; reg < 16; ++reg) {
            float v = acc[fm][0][reg] + acc[fm][1][reg];
            v += __shfl_xor(v, 1);
            v += __shfl_xor(v, 2);
            v += __shfl_xor(v, 4);
            v += __shfl_xor(v, 8);
            v += __shfl_xor(v, 16);
            if (lane31 == 0) {
                int rif = (reg & 3) + 8 * (reg >> 2) + 4 * kb;
                rbuf[wn][wm * 64 + fm * 32 + rif] = v;
            }
        }
    }
    // col sums over this wave's 64 rows (fm+reg in-lane, halves via xor32)
    #pragma unroll
    for (int fn = 0; fn < 2; ++fn) {
        float v = 0.f;
        #pragma unroll
        for (int fm = 0; fm < 2; ++fm)
            #pragma unroll
            for (int reg = 0; reg < 16; ++reg)
                v += acc[fm][fn][reg];
        v += __shfl_xor(v, 32);
        if (kb == 0) cbuf[wm][wn * 64 + fn * 32 + lane31] = v;
    }
    __syncthreads();
    if (tid < 128) {
        rp[(size_t)bj * 8192 + bi * 128 + tid] = rbuf[0][tid] + rbuf[1][tid];
        cp[(size_t)bi * 8192 + bj * 128 + tid] = cbuf[0][tid] + cbuf[1][tid];
    }
}

// ---- per-row logs, block partial sums ----
__global__ __launch_bounds__(256) void clip_fin1_k(const float* __restrict__ rp,
                                                   const float* __restrict__ cp,
                                                   const float* __restrict__ dg,
                                                   float* __restrict__ part) {
    int i = blockIdx.x * 256 + threadIdx.x;
    float rs = 0.f, cs = 0.f;
    #pragma unroll 8
    for (int b = 0; b < 64; ++b) rs += rp[(size_t)b * 8192 + i];
    #pragma unroll 8
    for (int b = 0; b < 64; ++b) cs += cp[(size_t)b * 8192 + i];
    float c = 0.5f * (logf(rs) + logf(cs)) - dg[i];
    #pragma unroll
    for (int o = 1; o < 64; o <<= 1) c += __shfl_xor(c, o);
    __shared__ float sb[4];
    if ((threadIdx.x & 63) == 0) sb[threadIdx.x >> 6] = c;
    __syncthreads();
    if (threadIdx.x == 0) part[blockIdx.x] = sb[0] + sb[1] + sb[2] + sb[3];
}

__global__ void clip_fin2_k(const float* __restrict__ part, float* __restrict__ out) {
    float v = (threadIdx.x < 32) ? part[threadIdx.x] : 0.f;
    #pragma unroll
    for (int o = 1; o < 64; o <<= 1) v += __shfl_xor(v, o);
    if (threadIdx.x == 0) out[0] = v * (1.f / 8192.f);
}

extern "C" void kernel_launch(void* const* d_in, const int* in_sizes, int n_in,
                              void* d_out, int out_size, void* d_ws, size_t ws_size,
                              hipStream_t stream) {
    const float* zi = (const float*)d_in[0];
    const float* zj = (const float*)d_in[1];
    float* out = (float*)d_out;
    char* ws = (char*)d_ws;

    unsigned int* zi8 = (unsigned int*)(ws);
    unsigned int* zj8 = (unsigned int*)(ws + (size_t)8 * 1024 * 1024);
    float* rp   = (float*)(ws + (size_t)16 * 1024 * 1024);   // 2 MB (64 panels)
    float* cp   = (float*)(ws + (size_t)18 * 1024 * 1024);   // 2 MB (64 panels)
    float* dg   = (float*)(ws + (size_t)20 * 1024 * 1024);
    float* part = (float*)(ws + (size_t)20 * 1024 * 1024 + 32768);

    clip_norm_k<<<8192, 256, 0, stream>>>(zi, zi8, 2.0f);   // temp x2 folded into zi
    clip_norm_k<<<8192, 256, 0, stream>>>(zj, zj8, 1.0f);
    clip_gemm_k<<<4096, 256, 0, stream>>>((const unsigned char*)zi8,
                                          (const unsigned char*)zj8, rp, cp, dg);
    clip_fin1_k<<<32, 256, 0, stream>>>(rp, cp, dg, part);
    clip_fin2_k<<<1, 64, 0, stream>>>(part, out);
}